// Round 7
// baseline (616.222 us; speedup 1.0000x reference)
//
#include <hip/hip_runtime.h>
#include <hip/hip_cooperative_groups.h>

namespace cg = cooperative_groups;

#define C 10
#define CHUNK_ROWS 128
#define CHUNK_FLOATS 1280
#define CHUNK_F4 320

__device__ __forceinline__ float waveSum(float v) {
#pragma unroll
  for (int o = 32; o > 0; o >>= 1) v += __shfl_down(v, o, 64);
  return v;
}
__device__ __forceinline__ float waveMin(float v) {
#pragma unroll
  for (int o = 32; o > 0; o >>= 1) v = fminf(v, __shfl_down(v, o, 64));
  return v;
}
__device__ __forceinline__ float waveMax(float v) {
#pragma unroll
  for (int o = 32; o > 0; o >>= 1) v = fmaxf(v, __shfl_down(v, o, 64));
  return v;
}
__device__ __forceinline__ unsigned waveMaxU(unsigned v) {
#pragma unroll
  for (int o = 32; o > 0; o >>= 1) {
    unsigned w = (unsigned)__shfl_down((int)v, o, 64);
    v = v > w ? v : w;
  }
  return v;
}

#define GLD16(gp, lp)                                             \
  __builtin_amdgcn_global_load_lds(                               \
      (__attribute__((address_space(1))) void*)(gp),              \
      (__attribute__((address_space(3))) void*)(lp), 16, 0, 0)

// per-sample weight+bin, shared by mega phase-2 and fallback pass2
__device__ __forceinline__ void binSample(unsigned b, const float* th,
                                          int& rb, int& j, float& wc, float& wu) {
  rb = (b >> 31) ? 44 : 0;
  float u = __uint_as_float(b & 0x7fffffffu);
  float e = u * 0.4342944819f;  // u / ln(10)
  float lnum = __logf(e * 0.9f);
  float lden = __logf(fmaxf((1.f - e) * 0.1f, 1e-10f));
  float x = fmaxf(lnum - lden, -23.0258509f) * 100.f;
  float s = __builtin_amdgcn_rcpf(1.f + __expf(-x));                   // sigmoid
  float t = 1.f - 2.f * __builtin_amdgcn_rcpf(__expf(2.f * u) + 1.f);  // tanh
  wc = (1.f - s) * (1.f - t);
  wu = s * t;
  j = 0;
#pragma unroll
  for (int k = 0; k < 21; ++k) j += (u > th[k]) ? 1 : 0;
}

// ================= cooperative mega-kernel: all three passes fused.
// Phase 1: 8 tiles x 512 rows per block, GLD16-staged (round-3 structure, the
// best measured); unc/acc archived in 16 VGPRs per thread -> NO us array.
// grid.sync -> phase 2 bins register-resident values into LDS hist -> spread
// slot atomics. grid.sync -> block 0 finalizes. LDS: hist 22528B aliases the
// 20480B stage tile. VGPR capped 128 by launch_bounds -> 4 blocks/CU >= the
// 1024/256 co-residency requirement.
__global__ __launch_bounds__(256, 4) void mega(
    const float* __restrict__ probs, const float* __restrict__ y,
    unsigned* __restrict__ uminInvSlots, unsigned* __restrict__ umaxSlots,
    float* __restrict__ ceSlots, float* __restrict__ focalSlots,
    float* __restrict__ ghist, float* __restrict__ out, float invN) {
  __shared__ float lds[88 * 64];  // 22528 B; [0,5120) floats = stage tile
  __shared__ float smm[2];
  const int tid = threadIdx.x, lane = tid & 63, widx = tid >> 6;
  cg::grid_group grid = cg::this_grid();

  int label0 = 0;  // argmax of flattened one-hot y == label of sample 0
  {
    float m = y[0];
#pragma unroll
    for (int c = 1; c < C; ++c) {
      float v = y[c];
      if (v > m) { m = v; label0 = c; }
    }
  }

  float au[16];  // archived unc|acc, 2 per tile
  float ceA = 0.f, foA = 0.f;
  float mnA = __uint_as_float(0x7f800000u), mxA = 0.f;
  const size_t blockBase = (size_t)blockIdx.x * (8 * 5120);
  const float2* b2 = (const float2*)lds;

#pragma unroll 1
  for (int t = 0; t < 8; ++t) {
    const size_t base = blockBase + (size_t)t * 5120;
#pragma unroll
    for (int k = 0; k < 5; ++k) {  // stage P tile (1280 f4, coalesced async)
      int idx = k * 256 + tid;
      GLD16(probs + base + (size_t)idx * 4, lds + idx * 4);
    }
    __syncthreads();  // P ready
    float P0[10], P1[10];  // rows tid, tid+256 (5 float2 each, 2-way bank = free)
#pragma unroll
    for (int j = 0; j < 5; ++j) {
      float2 v = b2[tid * 5 + j];
      P0[2 * j] = v.x; P0[2 * j + 1] = v.y;
      float2 w = b2[(tid + 256) * 5 + j];
      P1[2 * j] = w.x; P1[2 * j + 1] = w.y;
    }
    __syncthreads();  // all reads done -> buffer free
#pragma unroll
    for (int k = 0; k < 5; ++k) {  // stage Y into same buffer
      int idx = k * 256 + tid;
      GLD16(y + base + (size_t)idx * 4, lds + idx * 4);
    }
    // compute while Y is in flight
    int am0 = 0, am1 = 0;
    float m0 = P0[0], m1 = P1[0];
#pragma unroll
    for (int cc = 1; cc < C; ++cc) {  // strict > keeps first max (jnp.argmax)
      if (P0[cc] > m0) { m0 = P0[cc]; am0 = cc; }
      if (P1[cc] > m1) { m1 = P1[cc]; am1 = cc; }
    }
    float u0 = 0.f, u1 = 0.f;
#pragma unroll
    for (int cc = 0; cc < C; ++cc) {
      u0 -= P0[cc] * __logf(fmaxf(P0[cc], 1e-10f));
      u1 -= P1[cc] * __logf(fmaxf(P1[cc], 1e-10f));
    }
    mnA = fminf(mnA, fminf(u0, u1));
    mxA = fmaxf(mxA, fmaxf(u0, u1));
    au[2 * t] = __uint_as_float(__float_as_uint(u0) |
                                ((am0 == label0) ? 0u : 0x80000000u));
    au[2 * t + 1] = __uint_as_float(__float_as_uint(u1) |
                                    ((am1 == label0) ? 0u : 0x80000000u));
    __syncthreads();  // Y ready
    float pl0 = 0.f, pl1 = 0.f;  // one-hot dot -> p at true label
#pragma unroll
    for (int j = 0; j < 5; ++j) {
      float2 v = b2[tid * 5 + j];
      pl0 = fmaf(v.x, P0[2 * j], pl0); pl0 = fmaf(v.y, P0[2 * j + 1], pl0);
      float2 w = b2[(tid + 256) * 5 + j];
      pl1 = fmaf(w.x, P1[2 * j], pl1); pl1 = fmaf(w.y, P1[2 * j + 1], pl1);
    }
    float ce0 = -__logf(fmaxf(pl0, 1e-8f)), ce1 = -__logf(fmaxf(pl1, 1e-8f));
    ceA += ce0 + ce1;
    foA += ce0 * (1.f - pl0) + ce1 * (1.f - pl1);
    __syncthreads();  // buffer free for next tile
  }

  {  // per-wave reduce -> spread-slot device atomics
    float ce = waveSum(ceA), fo = waveSum(foA);
    float mn = waveMin(mnA), mx = waveMax(mxA);
    if (lane == 0) {
      int slot = (blockIdx.x * 4 + widx) & 63;
      atomicAdd(&ceSlots[slot], ce);
      atomicAdd(&focalSlots[slot], fo);
      atomicMax(&uminInvSlots[slot], ~__float_as_uint(mn));
      atomicMax(&umaxSlots[slot], __float_as_uint(mx));
    }
  }
  grid.sync();

  // ---- phase 2: bin the 16 archived values into LDS hist (per-lane columns)
  if (tid < 64) {
    unsigned mnInv = waveMaxU(uminInvSlots[tid]);
    unsigned mxb = waveMaxU(umaxSlots[tid]);
    if (tid == 0) { smm[0] = __uint_as_float(~mnInv); smm[1] = __uint_as_float(mxb); }
  }
  for (int i = tid; i < 88 * 64; i += 256) lds[i] = 0.f;
  __syncthreads();
  {
    const float umin = smm[0], delta = smm[1] - smm[0];
    float th[21];
#pragma unroll
    for (int k = 0; k < 21; ++k) th[k] = fmaf(0.05f * (float)k, delta, umin);
#pragma unroll
    for (int i = 0; i < 16; ++i) {
      int rb, j; float wc, wu;
      binSample(__float_as_uint(au[i]), th, rb, j, wc, wu);
      atomicAdd(&lds[(rb + j) * 64 + lane], wc);        // ds_add_f32
      atomicAdd(&lds[(rb + 22 + j) * 64 + lane], wu);
    }
  }
  __syncthreads();
#pragma unroll
  for (int st = 32; st >= 1; st >>= 1) {  // tree-reduce 64 columns per row
    for (int idx = tid; idx < 88 * st; idx += 256) {
      int r = idx / st, c = idx - r * st;
      lds[r * 64 + c] += lds[r * 64 + c + st];
    }
    __syncthreads();
  }
  {
    int slot = blockIdx.x & 63;
    for (int r = tid; r < 88; r += 256) atomicAdd(&ghist[slot * 88 + r], lds[r * 64]);
  }
  grid.sync();

  // ---- phase 3: block 0 finalizes
  if (blockIdx.x == 0) {
    if (tid < 88) {
      float s = 0.f;
      for (int q = 0; q < 64; ++q) s += ghist[q * 88 + tid];
      lds[tid] = s;
    }
    if (tid >= 128 && tid < 192) {
      int l = tid - 128;
      float ce = waveSum(ceSlots[l]);
      float fo = waveSum(focalSlots[l]);
      if (l == 0) { smm[0] = ce; smm[1] = fo; }
    }
    __syncthreads();
    if (tid == 0) {
      float totAU = 0.f, totIU = 0.f;
      for (int j = 0; j < 22; ++j) { totAU += lds[22 + j]; totIU += lds[66 + j]; }
      float n_ac = 0.f, n_ic = 0.f, n_au = totAU, n_iu = totIU;
      float auc = 0.f, prev = 0.f;
      for (int k = 0; k < 21; ++k) {
        n_ac += lds[k]; n_ic += lds[44 + k];
        n_au -= lds[22 + k]; n_iu -= lds[66 + k];
        float avu = (n_ac + n_iu) / (n_ac + n_au + n_ic + n_iu + 1e-10f);
        if (k > 0) auc += (avu + prev) * 0.5f * 0.05f;
        prev = avu;
      }
      out[0] = -logf(fmaxf(auc, 1e-10f)) + smm[1] * invN;
      out[1] = smm[0] * invN;
    }
  }
}

// ================= fallback (round-6 three-kernel path), used only if the
// cooperative launch is rejected (e.g. by graph capture).
__global__ __launch_bounds__(128, 4) void pass1(
    const float4* __restrict__ probs4, const float4* __restrict__ y4,
    float2* __restrict__ us2,
    unsigned* __restrict__ uminInvSlots, unsigned* __restrict__ umaxSlots,
    float* __restrict__ ceSlots, float* __restrict__ focalSlots,
    int nchunks) {
  __shared__ float lds[2 * 2 * CHUNK_FLOATS];
  const int widx = threadIdx.x >> 6, lane = threadIdx.x & 63;
  float4* const bufP = (float4*)(lds + widx * (2 * CHUNK_FLOATS));
  float4* const bufS = bufP + CHUNK_F4;
  const int gw = blockIdx.x * 2 + widx;
  const int NW = gridDim.x * 2;
  int label0 = 0;
  {
    const float* yf = (const float*)y4;
    float m = yf[0];
#pragma unroll
    for (int c = 1; c < C; ++c) {
      float v = yf[c];
      if (v > m) { m = v; label0 = c; }
    }
  }
  float4 P[5], Y[5];
  auto issue = [&](int c) {
    const float4* gp = probs4 + (size_t)c * CHUNK_F4 + lane;
    const float4* gy = y4 + (size_t)c * CHUNK_F4 + lane;
#pragma unroll
    for (int q = 0; q < 5; ++q) { P[q] = gp[q * 64]; Y[q] = gy[q * 64]; }
  };
  float ceA = 0.f, foA = 0.f;
  float mnA = __uint_as_float(0x7f800000u), mxA = 0.f;
  if (gw < nchunks) issue(gw);
  for (int c = gw; c < nchunks; c += NW) {
#pragma unroll
    for (int q = 0; q < 5; ++q) {
      float4 pv = P[q], yv = Y[q];
      float lpx = __logf(fmaxf(pv.x, 1e-10f));
      float lpy = __logf(fmaxf(pv.y, 1e-10f));
      float lpz = __logf(fmaxf(pv.z, 1e-10f));
      float lpw = __logf(fmaxf(pv.w, 1e-10f));
      float4 sv = make_float4(pv.x * lpx, pv.y * lpy, pv.z * lpz, pv.w * lpw);
      float tx = yv.x * fmaxf(lpx, -18.420681f);
      float ty = yv.y * fmaxf(lpy, -18.420681f);
      float tz = yv.z * fmaxf(lpz, -18.420681f);
      float tw = yv.w * fmaxf(lpw, -18.420681f);
      ceA -= tx + ty + tz + tw;
      foA -= tx * (1.f - pv.x) + ty * (1.f - pv.y) + tz * (1.f - pv.z) +
             tw * (1.f - pv.w);
      bufP[q * 64 + lane] = pv;
      bufS[q * 64 + lane] = sv;
    }
    if (c + NW < nchunks) issue(c + NW);
    float R[20], S[20];
#pragma unroll
    for (int q = 0; q < 5; ++q) {
      float4 v = bufP[lane * 5 + q];
      R[4 * q] = v.x; R[4 * q + 1] = v.y; R[4 * q + 2] = v.z; R[4 * q + 3] = v.w;
      float4 w = bufS[lane * 5 + q];
      S[4 * q] = w.x; S[4 * q + 1] = w.y; S[4 * q + 2] = w.z; S[4 * q + 3] = w.w;
    }
    int am0 = 0, am1 = 0;
    float m0 = R[0], m1 = R[10];
#pragma unroll
    for (int cc = 1; cc < C; ++cc) {
      if (R[cc] > m0) { m0 = R[cc]; am0 = cc; }
      if (R[10 + cc] > m1) { m1 = R[10 + cc]; am1 = cc; }
    }
    float u0 = -(((S[0] + S[1]) + (S[2] + S[3])) + ((S[4] + S[5]) + (S[6] + S[7])) +
                 (S[8] + S[9]));
    float u1 = -(((S[10] + S[11]) + (S[12] + S[13])) +
                 ((S[14] + S[15]) + (S[16] + S[17])) + (S[18] + S[19]));
    mnA = fminf(mnA, fminf(u0, u1));
    mxA = fmaxf(mxA, fmaxf(u0, u1));
    unsigned s0 = __float_as_uint(u0) | ((am0 == label0) ? 0u : 0x80000000u);
    unsigned s1 = __float_as_uint(u1) | ((am1 == label0) ? 0u : 0x80000000u);
    us2[(size_t)c * 64 + lane] = make_float2(__uint_as_float(s0), __uint_as_float(s1));
  }
  float ce = waveSum(ceA), fo = waveSum(foA);
  float mn = waveMin(mnA), mx = waveMax(mxA);
  if (lane == 0) {
    int slot = gw & 63;
    atomicAdd(&ceSlots[slot], ce);
    atomicAdd(&focalSlots[slot], fo);
    atomicMax(&uminInvSlots[slot], ~__float_as_uint(mn));
    atomicMax(&umaxSlots[slot], __float_as_uint(mx));
  }
}

__global__ __launch_bounds__(256, 4) void pass2(
    const float4* __restrict__ us4, int n4,
    const unsigned* __restrict__ uminInvSlots, const unsigned* __restrict__ umaxSlots,
    float* __restrict__ ghist) {
  __shared__ float hist[88 * 64];
  __shared__ float smm[2];
  const int tid = threadIdx.x, lane = tid & 63;
  for (int i = tid; i < 88 * 64; i += 256) hist[i] = 0.f;
  if (tid < 64) {
    unsigned mnInv = waveMaxU(uminInvSlots[tid]);
    unsigned mxb = waveMaxU(umaxSlots[tid]);
    if (tid == 0) { smm[0] = __uint_as_float(~mnInv); smm[1] = __uint_as_float(mxb); }
  }
  __syncthreads();
  const float umin = smm[0], delta = smm[1] - smm[0];
  float th[21];
#pragma unroll
  for (int k = 0; k < 21; ++k) th[k] = fmaf(0.05f * (float)k, delta, umin);
  const int stride = gridDim.x * 256;
  for (int i = blockIdx.x * 256 + tid; i < n4; i += stride) {
    float4 v = us4[i];
    float vv[4] = {v.x, v.y, v.z, v.w};
#pragma unroll
    for (int q = 0; q < 4; ++q) {
      int rb, j; float wc, wu;
      binSample(__float_as_uint(vv[q]), th, rb, j, wc, wu);
      atomicAdd(&hist[(rb + j) * 64 + lane], wc);
      atomicAdd(&hist[(rb + 22 + j) * 64 + lane], wu);
    }
  }
  __syncthreads();
#pragma unroll
  for (int st = 32; st >= 1; st >>= 1) {
    for (int idx = tid; idx < 88 * st; idx += 256) {
      int r = idx / st, c = idx - r * st;
      hist[r * 64 + c] += hist[r * 64 + c + st];
    }
    __syncthreads();
  }
  int slot = blockIdx.x & 63;
  for (int r = tid; r < 88; r += 256) atomicAdd(&ghist[slot * 88 + r], hist[r * 64]);
}

__global__ __launch_bounds__(256) void pass3(
    const float* __restrict__ ghist,
    const float* __restrict__ ceSlots, const float* __restrict__ focalSlots,
    float* __restrict__ out, float invN) {
  __shared__ float hr[88];
  __shared__ float scf[2];
  int tid = threadIdx.x;
  if (tid < 88) {
    float s = 0.f;
    for (int q = 0; q < 64; ++q) s += ghist[q * 88 + tid];
    hr[tid] = s;
  }
  if (tid >= 128 && tid < 192) {
    int l = tid - 128;
    float ce = waveSum(ceSlots[l]);
    float fo = waveSum(focalSlots[l]);
    if (l == 0) { scf[0] = ce; scf[1] = fo; }
  }
  __syncthreads();
  if (tid == 0) {
    float totAU = 0.f, totIU = 0.f;
    for (int j = 0; j < 22; ++j) { totAU += hr[22 + j]; totIU += hr[66 + j]; }
    float n_ac = 0.f, n_ic = 0.f, n_au = totAU, n_iu = totIU;
    float auc = 0.f, prev = 0.f;
    for (int k = 0; k < 21; ++k) {
      n_ac += hr[k]; n_ic += hr[44 + k];
      n_au -= hr[22 + k]; n_iu -= hr[66 + k];
      float avu = (n_ac + n_iu) / (n_ac + n_au + n_ic + n_iu + 1e-10f);
      if (k > 0) auc += (avu + prev) * 0.5f * 0.05f;
      prev = avu;
    }
    out[0] = -logf(fmaxf(auc, 1e-10f)) + scf[1] * invN;
    out[1] = scf[0] * invN;
  }
}

extern "C" void kernel_launch(void* const* d_in, const int* in_sizes, int n_in,
                              void* d_out, int out_size, void* d_ws, size_t ws_size,
                              hipStream_t stream) {
  const float* probs = (const float*)d_in[0];
  const float* y = (const float*)d_in[1];
  float* out = (float*)d_out;
  const int N = in_sizes[0] / C;
  float invN = 1.0f / (float)N;

  float* wsf = (float*)d_ws;
  unsigned* uminInvSlots = (unsigned*)wsf;
  unsigned* umaxSlots = (unsigned*)(wsf + 64);
  float* ceSlots = wsf + 128;
  float* focalSlots = wsf + 192;
  float* ghist = wsf + 256;
  float* us = wsf + 5888;  // fallback only

  hipMemsetAsync(d_ws, 0, 5888 * sizeof(float), stream);

  void* args[] = {(void*)&probs, (void*)&y, (void*)&uminInvSlots,
                  (void*)&umaxSlots, (void*)&ceSlots, (void*)&focalSlots,
                  (void*)&ghist, (void*)&out, (void*)&invN};
  hipError_t e = hipLaunchCooperativeKernel((const void*)mega, dim3(1024),
                                            dim3(256), args, 0, stream);
  if (e != hipSuccess) {
    // fallback: three-kernel path (identical result)
    const int nchunks = N / CHUNK_ROWS;
    pass1<<<2048, 128, 0, stream>>>((const float4*)probs, (const float4*)y,
                                    (float2*)us, uminInvSlots, umaxSlots,
                                    ceSlots, focalSlots, nchunks);
    pass2<<<1024, 256, 0, stream>>>((const float4*)us, N / 4, uminInvSlots,
                                    umaxSlots, ghist);
    pass3<<<1, 256, 0, stream>>>(ghist, ceSlots, focalSlots, out, invN);
  }
}